// Round 4
// baseline (31.673 us; speedup 1.0000x reference)
//
#include <hip/hip_runtime.h>

#define NS 64            // samples = 32 batches * 2 channels
#define HH 640
#define WW 640
#define NPIX (HH * WW)   // 409600
#define TH 320
#define TW 320
#define MINK 10
#define BPS 80           // blocks per sample (8 rows each)
#define TPB 320          // 4 rows x 80 u-slots, 5 waves
// each thread: 2 row-steps of 4 rows => 8 rows, 8 px per row-step => 16 px

// exact scalar bilinear tap (half-pixel centers, edge clamp) — fallback path only
__device__ __forceinline__ float resize_scalar(const float* __restrict__ tgt, int y, int xc) {
    float sy = fmaxf(0.5f * (float)y - 0.25f, 0.0f);
    int y0 = (int)sy;
    float fy = sy - (float)y0;
    int y1 = min(y0 + 1, TH - 1);
    float sx = fmaxf(0.5f * (float)xc - 0.25f, 0.0f);
    int x0 = (int)sx;
    float fx = sx - (float)x0;
    int x1 = min(x0 + 1, TW - 1);
    const float* r0 = tgt + y0 * TW;
    const float* r1 = tgt + y1 * TW;
    float top = (1.0f - fx) * r0[x0] + fx * r0[x1];
    float bot = (1.0f - fx) * r1[x0] + fx * r1[x1];
    return (1.0f - fy) * top + fy * bot;
}

// x-interp helper: 6 y-blended source cols -> 8 output tv + accumulate loss
__device__ __forceinline__ void acc8(const float4& pa, const float4& pb,
                                     float mL, float m0, float m1, float m2, float m3, float mR,
                                     float& sA, float& sP, int& cP) {
    float tv[8];
    tv[0] = 0.25f * mL + 0.75f * m0;
    tv[1] = 0.75f * m0 + 0.25f * m1;
    tv[2] = 0.25f * m0 + 0.75f * m1;
    tv[3] = 0.75f * m1 + 0.25f * m2;
    tv[4] = 0.25f * m1 + 0.75f * m2;
    tv[5] = 0.75f * m2 + 0.25f * m3;
    tv[6] = 0.25f * m2 + 0.75f * m3;
    tv[7] = 0.75f * m3 + 0.25f * mR;
    float pv[8] = {pa.x, pa.y, pa.z, pa.w, pb.x, pb.y, pb.z, pb.w};
#pragma unroll
    for (int j = 0; j < 8; ++j) {
        float d = pv[j] - tv[j];
        float l = d * d;
        sA += l;
        bool pos = tv[j] > 0.0f;
        sP += pos ? l : 0.0f;
        cP += pos ? 1 : 0;
    }
}

// ---------------- pass 1: per-sample streaming reduction ----------------
// All loads issued before any compute (max MLP); per-block partials.
__global__ __launch_bounds__(TPB, 6) void k_reduce(const float* __restrict__ x,
                                                   const float* __restrict__ ct,
                                                   const float* __restrict__ at,
                                                   float* __restrict__ partA,
                                                   float* __restrict__ partP,
                                                   int* __restrict__ partC) {
    int bid = blockIdx.x;
    int s = bid / BPS, blk = bid % BPS;
    int b = s >> 1, c = s & 1;
    const float* pred = x + (size_t)s * NPIX;
    const float* tgt = (c == 0 ? ct : at) + (size_t)b * (TH * TW);

    int tid = threadIdx.x;
    int u = tid % 80;        // output col group: x = 8u..8u+7
    int rr = tid / 80;       // 0..3
    int rbase = blk * 8;

    // y parity = rr parity (rbase even): fy fixed per thread
    float fy = (rr & 1) ? 0.25f : 0.75f;
    float gy = 1.0f - fy;
    int xq = 4 * u;
    int xl = max(xq - 1, 0);
    int xr = min(xq + 4, TW - 1);

    // ---- issue ALL loads up front ----
    int ya = rbase + rr;         // iter 0 output row
    int yb = ya + 4;             // iter 1 output row
    const float* pra = pred + ya * WW + 8 * u;
    const float* prb = pred + yb * WW + 8 * u;
    float4 pa0 = *reinterpret_cast<const float4*>(pra);
    float4 pa1 = *reinterpret_cast<const float4*>(pra + 4);
    float4 pb0 = *reinterpret_cast<const float4*>(prb);
    float4 pb1 = *reinterpret_cast<const float4*>(prb + 4);

    // tgt rows: y0raw = (y>>1)+(y&1)-1; clamp both ends (== resize edge semantics)
    int a0raw = (ya >> 1) + (ya & 1) - 1;
    int aT = max(a0raw, 0), aB = min(a0raw + 1, TH - 1);
    int b0raw = (yb >> 1) + (yb & 1) - 1;
    int bT = max(b0raw, 0), bB = min(b0raw + 1, TH - 1);
    const float* rAT = tgt + aT * TW;
    const float* rAB = tgt + aB * TW;
    const float* rBT = tgt + bT * TW;
    const float* rBB = tgt + bB * TW;

    float4 qAT = *reinterpret_cast<const float4*>(rAT + xq);
    float4 qAB = *reinterpret_cast<const float4*>(rAB + xq);
    float4 qBT = *reinterpret_cast<const float4*>(rBT + xq);
    float4 qBB = *reinterpret_cast<const float4*>(rBB + xq);
    float LAT = rAT[xl], RAT = rAT[xr];
    float LAB = rAB[xl], RAB = rAB[xr];
    float LBT = rBT[xl], RBT = rBT[xr];
    float LBB = rBB[xl], RBB = rBB[xr];

    // ---- compute ----
    float sA = 0.0f, sP = 0.0f;
    int cP = 0;

    // iter 0: y-blend then x-interp
    acc8(pa0, pa1,
         gy * LAT + fy * LAB,
         gy * qAT.x + fy * qAB.x,
         gy * qAT.y + fy * qAB.y,
         gy * qAT.z + fy * qAB.z,
         gy * qAT.w + fy * qAB.w,
         gy * RAT + fy * RAB,
         sA, sP, cP);
    // iter 1
    acc8(pb0, pb1,
         gy * LBT + fy * LBB,
         gy * qBT.x + fy * qBB.x,
         gy * qBT.y + fy * qBB.y,
         gy * qBT.z + fy * qBB.z,
         gy * qBT.w + fy * qBB.w,
         gy * RBT + fy * RBB,
         sA, sP, cP);

    // wave64 shuffle reduce + LDS block reduce (5 waves)
    for (int off = 32; off > 0; off >>= 1) {
        sA += __shfl_down(sA, off);
        sP += __shfl_down(sP, off);
        cP += __shfl_down(cP, off);
    }
    __shared__ float shA[5], shP[5];
    __shared__ int shC[5];
    int w = tid >> 6;
    if ((tid & 63) == 0) { shA[w] = sA; shP[w] = sP; shC[w] = cP; }
    __syncthreads();
    if (tid == 0) {
        float a = 0.0f, p = 0.0f;
        int ci = 0;
        for (int q = 0; q < 5; ++q) { a += shA[q]; p += shP[q]; ci += shC[q]; }
        partA[s * BPS + blk] = a;
        partP[s * BPS + blk] = p;
        partC[s * BPS + blk] = ci;
    }
}

// ---------------- pass 2 (rare fallback): exact top-k when k < N-p ----------------
// 3-pass bit-histogram selection over losses of negative-target elements.
// Early-exits for this data regime (p ~ N/2 >> N/4).
__global__ __launch_bounds__(256) void k_topk(const float* __restrict__ x,
                                              const float* __restrict__ ct,
                                              const float* __restrict__ at,
                                              const int* __restrict__ partC,
                                              float* __restrict__ topk) {
    int s = blockIdx.x;
    __shared__ int pSh;
    if (threadIdx.x < 64) {
        int t = threadIdx.x;
        int v = partC[s * BPS + t];
        if (t < BPS - 64) v += partC[s * BPS + 64 + t];
        for (int off = 32; off > 0; off >>= 1) v += __shfl_down(v, off);
        if (t == 0) pSh = v;
    }
    __syncthreads();
    int p = pSh;
    int k = min((int)((float)p * 3.0f), NPIX - p);
    if (k < MINK || k >= NPIX - p) return;   // simple paths handled in k_final

    int b = s >> 1, c = s & 1;
    const float* pred = x + (size_t)s * NPIX;
    const float* tgt = (c == 0 ? ct : at) + (size_t)b * (TH * TW);

    __shared__ unsigned int hcnt[2048];
    __shared__ float hsum[2048];
    __shared__ unsigned int selBin;
    __shared__ unsigned int remShared;
    __shared__ float sumTopShared;

    if (threadIdx.x == 0) { remShared = (unsigned int)k; sumTopShared = 0.0f; }

    const int shiftv[3] = {21, 10, 0};
    const unsigned int maskv[3] = {0x7FFu, 0x7FFu, 0x3FFu};
    unsigned int prefix = 0;

    for (int pass = 0; pass < 3; ++pass) {
        for (int i = threadIdx.x; i < 2048; i += 256) { hcnt[i] = 0u; hsum[i] = 0.0f; }
        __syncthreads();
        for (int e = threadIdx.x; e < NPIX; e += 256) {
            int yy = e / WW, xx = e % WW;
            float tv = resize_scalar(tgt, yy, xx);
            if (tv > 0.0f) continue;          // positives excluded (-inf in ref)
            float d = pred[e] - tv;
            float l = d * d;                  // >= 0: uint bits order-preserving
            unsigned int bits = __float_as_uint(l);
            bool match;
            if (pass == 0) match = true;
            else if (pass == 1) match = ((bits >> 21) == prefix);
            else match = ((bits >> 10) == prefix);
            if (match) {
                unsigned int bin = (bits >> shiftv[pass]) & maskv[pass];
                atomicAdd(&hcnt[bin], 1u);
                atomicAdd(&hsum[bin], l);
            }
        }
        __syncthreads();
        if (threadIdx.x == 0) {
            unsigned int remS = remShared;
            int nb = (int)maskv[pass] + 1;
            unsigned int cum = 0; float sAbove = 0.0f; unsigned int bsel = 0;
            for (int bin = nb - 1; bin >= 0; --bin) {
                unsigned int cc = hcnt[bin];
                if (cum + cc >= remS) { bsel = (unsigned int)bin; break; }
                cum += cc; sAbove += hsum[bin];
            }
            selBin = bsel;
            remShared = remS - cum;
            sumTopShared += sAbove;
        }
        __syncthreads();
        if (pass == 0) prefix = selBin;
        else if (pass == 1) prefix = (prefix << 11) | selBin;
        __syncthreads();
    }
    if (threadIdx.x == 0) {
        unsigned int bits = (prefix << 10) | selBin;  // exact k-th largest value
        float v = __uint_as_float(bits);
        topk[s] = sumTopShared + (float)remShared * v;
    }
}

// ---------------- pass 3: sum partials, per-sample OHEM logic, final mean ----------------
__global__ void k_final(const float* __restrict__ partA, const float* __restrict__ partP,
                        const int* __restrict__ partC, const float* __restrict__ topk,
                        float* __restrict__ out) {
    int s = threadIdx.x;   // 64 threads == 1 wave
    float a = 0.0f, pp = 0.0f;
    int p = 0;
    const float4* pa4 = reinterpret_cast<const float4*>(partA + s * BPS);
    const float4* pp4 = reinterpret_cast<const float4*>(partP + s * BPS);
    const int4*   pc4 = reinterpret_cast<const int4*>(partC + s * BPS);
#pragma unroll
    for (int q = 0; q < BPS / 4; ++q) {
        float4 va = pa4[q]; a += va.x + va.y + va.z + va.w;
        float4 vp = pp4[q]; pp += vp.x + vp.y + vp.z + vp.w;
        int4 vc = pc4[q]; p += vc.x + vc.y + vc.z + vc.w;
    }
    int k = min((int)((float)p * 3.0f), NPIX - p);  // exact: 3p < 2^24
    float lossv;
    if (k < MINK) {
        lossv = a / (float)NPIX;
    } else {
        float nn = a - pp;                           // sumNeg
        float tsum = (k >= NPIX - p) ? nn : topk[s];
        lossv = pp / (float)max(p, 1) + tsum / (float)max(k, 1);
    }
    for (int off = 32; off > 0; off >>= 1) lossv += __shfl_down(lossv, off);
    if (s == 0) out[0] = lossv / 32.0f;   // mean over B of (char + aff)
}

extern "C" void kernel_launch(void* const* d_in, const int* in_sizes, int n_in,
                              void* d_out, int out_size, void* d_ws, size_t ws_size,
                              hipStream_t stream) {
    const float* x  = (const float*)d_in[0];
    const float* ct = (const float*)d_in[1];
    const float* at = (const float*)d_in[2];
    float* out = (float*)d_out;

    float* partA = (float*)d_ws;                 // NS*BPS floats
    float* partP = partA + NS * BPS;             // NS*BPS floats
    int*   partC = (int*)(partP + NS * BPS);     // NS*BPS ints
    float* topk  = (float*)(partC + NS * BPS);   // NS floats

    k_reduce<<<dim3(NS * BPS), dim3(TPB), 0, stream>>>(x, ct, at, partA, partP, partC);
    k_topk<<<dim3(NS), dim3(256), 0, stream>>>(x, ct, at, partC, topk);
    k_final<<<dim3(1), dim3(64), 0, stream>>>(partA, partP, partC, topk, out);
}